// Round 1
// baseline (264.298 us; speedup 1.0000x reference)
//
#include <hip/hip_runtime.h>
#include <hip/hip_bf16.h>

// StochasticEnsemble: hard-routed 8-expert MLP.
//   idx[i] = (sum_j floor(|z[i,j]|*1000)) % 8   (exact fp32 integer arithmetic)
//   h = relu(z @ W1[e] + b1[e]);  out = h @ W2[e] + b2[e]   (bf16 MFMA, fp32 acc)
// Strategy: bucket samples by expert, pad each expert's row range to a 64-row
// tile boundary, run two tiled MFMA GEMMs over the gathered rows.

#define BATCH 2048
#define ZD 128
#define HID 1024
#define OUTD 3072
#define NEXP 8
#define TM 64
#define TN 64
#define BK 32
#define LDA 40              // BK + 8 pad (elems), 80B row stride (16B aligned)
#define LDB 40
#define MAXROWS (BATCH + NEXP * TM)   // 2560 padded gathered rows max
#define MAXT (MAXROWS / TM)           // 40 M-tiles max

typedef short bf16x8 __attribute__((ext_vector_type(8)));   // 8 bf16 = 4 VGPRs
typedef float f32x4 __attribute__((ext_vector_type(4)));

// ---- workspace byte layout ----
// 0      counts[8]
// 64     ntiles (1 int)
// 128    tile_expert[MAXT]
// 384    perm[MAXROWS]
// 10624  bucket[8*2048]
// 76288  H bf16 [MAXROWS * HID]   (16B aligned)

__global__ void init_kernel(int* counts) {
    if (threadIdx.x < NEXP) counts[threadIdx.x] = 0;
}

__global__ __launch_bounds__(256) void route_kernel(const float* __restrict__ z,
                                                    int* counts, int* bucket) {
    int gid = blockIdx.x * 256 + threadIdx.x;
    int s_idx = gid >> 6;      // one wave per sample
    int lane = gid & 63;
    float a = z[s_idx * ZD + lane];
    float b = z[s_idx * ZD + 64 + lane];
    float s = floorf(fabsf(a) * 1000.0f) + floorf(fabsf(b) * 1000.0f);
#pragma unroll
    for (int off = 32; off > 0; off >>= 1) s += __shfl_down(s, off);
    if (lane == 0) {
        int e = ((int)s) & 7;
        int pos = atomicAdd(&counts[e], 1);
        bucket[e * BATCH + pos] = s_idx;
    }
}

__global__ void scan_kernel(const int* __restrict__ counts, int* ntiles,
                            int* texp, int* perm, const int* __restrict__ bucket) {
    __shared__ int soff[NEXP + 1];
    __shared__ int scnt[NEXP];
    if (threadIdx.x == 0) {
        int o = 0;
        for (int e = 0; e < NEXP; e++) {
            scnt[e] = counts[e];
            soff[e] = o;
            o += (scnt[e] + TM - 1) & ~(TM - 1);
        }
        soff[NEXP] = o;
        *ntiles = o / TM;
    }
    __syncthreads();
    int total = soff[NEXP];
    for (int r = threadIdx.x; r < total; r += blockDim.x) {
        int e = 0;
        while (r >= soff[e + 1]) e++;
        int i = r - soff[e];
        perm[r] = (i < scnt[e]) ? bucket[e * BATCH + i] : -1;
        if ((r & (TM - 1)) == 0) texp[r / TM] = e;
    }
}

// GEMM1: H[r,:] = relu(z[perm[r],:] @ W1[e] + b1[e]),  M=padded, N=1024, K=128
__global__ __launch_bounds__(256) void gemm1_kernel(
    const float* __restrict__ z, const float* __restrict__ W1,
    const float* __restrict__ b1, const int* __restrict__ ntiles,
    const int* __restrict__ texp, const int* __restrict__ perm,
    __hip_bfloat16* __restrict__ H) {
    int mt = blockIdx.x;
    if (mt >= *ntiles) return;
    int nt = blockIdx.y;
    int e = texp[mt];
    const float* W = W1 + (size_t)e * ZD * HID;
    int n0 = nt * TN;

    __shared__ __align__(16) __hip_bfloat16 As[TM][LDA];
    __shared__ __align__(16) __hip_bfloat16 Bs[TN][LDB];   // transposed: [n][k]
    __shared__ int rows[TM];

    int tid = threadIdx.x;
    if (tid < TM) rows[tid] = perm[mt * TM + tid];
    __syncthreads();

    int lane = tid & 63;
    int wave = tid >> 6;
    int mw = (wave >> 1) * 32;
    int nw = (wave & 1) * 32;

    f32x4 acc00 = {0.f, 0.f, 0.f, 0.f}, acc01 = acc00, acc10 = acc00, acc11 = acc00;

    int ar = tid >> 2, ak = (tid & 3) * 8;   // A stage: 8 f32 per thread
    int bk = tid >> 3, bn = (tid & 7) * 8;   // B stage: 8 f32 per thread
    int arow = rows[ar];

    for (int k0 = 0; k0 < ZD; k0 += BK) {
        float va[8];
        if (arow >= 0) {
            const float4* p = (const float4*)(z + (size_t)arow * ZD + k0 + ak);
            float4 v0 = p[0], v1 = p[1];
            va[0] = v0.x; va[1] = v0.y; va[2] = v0.z; va[3] = v0.w;
            va[4] = v1.x; va[5] = v1.y; va[6] = v1.z; va[7] = v1.w;
        } else {
#pragma unroll
            for (int j = 0; j < 8; j++) va[j] = 0.f;
        }
        const float4* q = (const float4*)(W + (size_t)(k0 + bk) * HID + n0 + bn);
        float4 w0 = q[0], w1 = q[1];
        float vb[8] = {w0.x, w0.y, w0.z, w0.w, w1.x, w1.y, w1.z, w1.w};

#pragma unroll
        for (int j = 0; j < 8; j++) As[ar][ak + j] = __float2bfloat16(va[j]);
#pragma unroll
        for (int j = 0; j < 8; j++) Bs[bn + j][bk] = __float2bfloat16(vb[j]);
        __syncthreads();

        bf16x8 a0 = *(const bf16x8*)&As[mw + (lane & 15)][(lane >> 4) * 8];
        bf16x8 a1 = *(const bf16x8*)&As[mw + 16 + (lane & 15)][(lane >> 4) * 8];
        bf16x8 b0 = *(const bf16x8*)&Bs[nw + (lane & 15)][(lane >> 4) * 8];
        bf16x8 b1v = *(const bf16x8*)&Bs[nw + 16 + (lane & 15)][(lane >> 4) * 8];
        acc00 = __builtin_amdgcn_mfma_f32_16x16x32_bf16(a0, b0, acc00, 0, 0, 0);
        acc01 = __builtin_amdgcn_mfma_f32_16x16x32_bf16(a0, b1v, acc01, 0, 0, 0);
        acc10 = __builtin_amdgcn_mfma_f32_16x16x32_bf16(a1, b0, acc10, 0, 0, 0);
        acc11 = __builtin_amdgcn_mfma_f32_16x16x32_bf16(a1, b1v, acc11, 0, 0, 0);
        __syncthreads();
    }

    const float* bias = b1 + (size_t)e * HID + n0;
    int cc = lane & 15;
    int rbase = (lane >> 4) * 4;
    f32x4 accs[2][2] = {{acc00, acc01}, {acc10, acc11}};
#pragma unroll
    for (int mi = 0; mi < 2; mi++)
#pragma unroll
        for (int ni = 0; ni < 2; ni++)
#pragma unroll
            for (int r = 0; r < 4; r++) {
                int rr = mw + mi * 16 + rbase + r;
                int nn = nw + ni * 16 + cc;
                float v = accs[mi][ni][r] + bias[nn];
                H[(size_t)(mt * TM + rr) * HID + n0 + nn] =
                    __float2bfloat16(fmaxf(v, 0.f));
            }
}

// GEMM2: out[perm[r],:] = H[r,:] @ W2[e] + b2[e],  M=padded, N=3072, K=1024
__global__ __launch_bounds__(256) void gemm2_kernel(
    const __hip_bfloat16* __restrict__ H, const float* __restrict__ W2,
    const float* __restrict__ b2, const int* __restrict__ ntiles,
    const int* __restrict__ texp, const int* __restrict__ perm,
    float* __restrict__ out) {
    int mt = blockIdx.x;
    if (mt >= *ntiles) return;
    int nt = blockIdx.y;
    int e = texp[mt];
    const float* W = W2 + (size_t)e * HID * OUTD;
    int n0 = nt * TN;

    __shared__ __align__(16) __hip_bfloat16 As[TM][LDA];
    __shared__ __align__(16) __hip_bfloat16 Bs[TN][LDB];   // transposed: [n][k]
    __shared__ int rows[TM];

    int tid = threadIdx.x;
    if (tid < TM) rows[tid] = perm[mt * TM + tid];
    __syncthreads();

    int lane = tid & 63;
    int wave = tid >> 6;
    int mw = (wave >> 1) * 32;
    int nw = (wave & 1) * 32;

    f32x4 acc00 = {0.f, 0.f, 0.f, 0.f}, acc01 = acc00, acc10 = acc00, acc11 = acc00;

    int ar = tid >> 2, ak = (tid & 3) * 8;   // A stage: 8 bf16 (16B) per thread
    int bk = tid >> 3, bn = (tid & 7) * 8;   // B stage: 8 f32 per thread
    const __hip_bfloat16* Hrow = H + (size_t)(mt * TM + ar) * HID;

    for (int k0 = 0; k0 < HID; k0 += BK) {
        float4 araw = *(const float4*)(Hrow + k0 + ak);   // 8 bf16 raw copy
        const float4* q = (const float4*)(W + (size_t)(k0 + bk) * OUTD + n0 + bn);
        float4 w0 = q[0], w1 = q[1];
        float vb[8] = {w0.x, w0.y, w0.z, w0.w, w1.x, w1.y, w1.z, w1.w};

        *(float4*)&As[ar][ak] = araw;
#pragma unroll
        for (int j = 0; j < 8; j++) Bs[bn + j][bk] = __float2bfloat16(vb[j]);
        __syncthreads();

        bf16x8 a0 = *(const bf16x8*)&As[mw + (lane & 15)][(lane >> 4) * 8];
        bf16x8 a1 = *(const bf16x8*)&As[mw + 16 + (lane & 15)][(lane >> 4) * 8];
        bf16x8 b0 = *(const bf16x8*)&Bs[nw + (lane & 15)][(lane >> 4) * 8];
        bf16x8 b1v = *(const bf16x8*)&Bs[nw + 16 + (lane & 15)][(lane >> 4) * 8];
        acc00 = __builtin_amdgcn_mfma_f32_16x16x32_bf16(a0, b0, acc00, 0, 0, 0);
        acc01 = __builtin_amdgcn_mfma_f32_16x16x32_bf16(a0, b1v, acc01, 0, 0, 0);
        acc10 = __builtin_amdgcn_mfma_f32_16x16x32_bf16(a1, b0, acc10, 0, 0, 0);
        acc11 = __builtin_amdgcn_mfma_f32_16x16x32_bf16(a1, b1v, acc11, 0, 0, 0);
        __syncthreads();
    }

    const float* bias = b2 + (size_t)e * OUTD + n0;
    int cc = lane & 15;
    int rbase = (lane >> 4) * 4;
    f32x4 accs[2][2] = {{acc00, acc01}, {acc10, acc11}};
#pragma unroll
    for (int mi = 0; mi < 2; mi++)
#pragma unroll
        for (int ni = 0; ni < 2; ni++)
#pragma unroll
            for (int r = 0; r < 4; r++) {
                int rr = mw + mi * 16 + rbase + r;
                int orow = rows[rr];
                if (orow >= 0) {
                    int nn = nw + ni * 16 + cc;
                    out[(size_t)orow * OUTD + n0 + nn] = accs[mi][ni][r] + bias[nn];
                }
            }
}

extern "C" void kernel_launch(void* const* d_in, const int* in_sizes, int n_in,
                              void* d_out, int out_size, void* d_ws, size_t ws_size,
                              hipStream_t stream) {
    const float* z  = (const float*)d_in[0];
    const float* W1 = (const float*)d_in[1];
    const float* b1 = (const float*)d_in[2];
    const float* W2 = (const float*)d_in[3];
    const float* b2 = (const float*)d_in[4];
    float* out = (float*)d_out;

    char* ws = (char*)d_ws;
    int* counts = (int*)ws;
    int* ntl    = (int*)(ws + 64);
    int* texp   = (int*)(ws + 128);
    int* perm   = (int*)(ws + 384);
    int* bucket = (int*)(ws + 10624);
    __hip_bfloat16* H = (__hip_bfloat16*)(ws + 76288);   // 5.25 MB, ends ~5.32 MB

    hipLaunchKernelGGL(init_kernel, dim3(1), dim3(64), 0, stream, counts);
    hipLaunchKernelGGL(route_kernel, dim3(BATCH / 4), dim3(256), 0, stream,
                       z, counts, bucket);
    hipLaunchKernelGGL(scan_kernel, dim3(1), dim3(256), 0, stream,
                       counts, ntl, texp, perm, bucket);
    hipLaunchKernelGGL(gemm1_kernel, dim3(MAXT, HID / TN), dim3(256), 0, stream,
                       z, W1, b1, ntl, texp, perm, H);
    hipLaunchKernelGGL(gemm2_kernel, dim3(MAXT, OUTD / TN), dim3(256), 0, stream,
                       H, W2, b2, ntl, texp, perm, out);
}